// Round 16
// baseline (142.124 us; speedup 1.0000x reference)
//
#include <hip/hip_runtime.h>
#include <hip/hip_bf16.h>
#include <stdint.h>

#define N 8192
#define D 512
#define TILE 128
#define BK 64
#define NKC (D / BK)                  // 8 K-chunks
#define NTB (N / TILE)                // 64 tile-rows (= #slices)
#define NBLK (NTB * (NTB + 1) / 2)    // 2080 upper-tri blocks
#define PANEL_BYTES (TILE * D)        // 65536 B per 128-row i8 panel
#define KCHUNK_BYTES (TILE * BK)      // 8192 B per staged i8 tile

typedef __attribute__((ext_vector_type(4))) int v4i;

// async global->LDS, 16B per lane; LDS dest = wave-uniform base + lane*16
__device__ __forceinline__ void gload_lds16(const void* gp, const void* lp) {
    auto g = (const __attribute__((address_space(1))) void*)(uintptr_t)gp;
    auto l = (__attribute__((address_space(3))) void*)(uintptr_t)lp;
    __builtin_amdgcn_global_load_lds(g, l, 16, 0, 0);
}

// Fn2 swizzled int8 layout (R15-verified datapath):
//   byte(p, kc, q, lr, ko) = p*65536 + kc*8192 + q*2048 + lr*16 + ko
// where p=row>>7, lr=row&127, k = kc*64 + q*16 + ko (ko in [0,16)).
// values = int8(round(127 * normalized_row)).
// g[row] = sqrt(10*log2(e)) / |q_row|  -> e = exp2(dot_q * g_i * g_j),
// which makes the diagonal EXACTLY e^10 (kills the i8 norm-bias that
// failed R15 at absmax 64 vs 55.36).
__global__ void cc_normalize(const float* __restrict__ F, uint8_t* __restrict__ Fn2,
                             float* __restrict__ g, float* __restrict__ out) {
    if (blockIdx.x == 0 && threadIdx.x == 0) out[0] = 0.0f;
    const int row  = blockIdx.x * 4 + (threadIdx.x >> 6);
    const int lane = threadIdx.x & 63;      // lane covers k = lane*8 .. +7
    const float* p = F + (size_t)row * D + lane * 8;
    float4 a = *(const float4*)p;
    float4 b = *(const float4*)(p + 4);
    float ss = a.x*a.x + a.y*a.y + a.z*a.z + a.w*a.w
             + b.x*b.x + b.y*b.y + b.z*b.z + b.w*b.w;
    #pragma unroll
    for (int m = 32; m; m >>= 1) ss += __shfl_xor(ss, m, 64);
    const float inv = 127.0f / fmaxf(sqrtf(ss), 1e-12f);

    int qv[8];
    qv[0] = __float2int_rn(a.x * inv);  qv[1] = __float2int_rn(a.y * inv);
    qv[2] = __float2int_rn(a.z * inv);  qv[3] = __float2int_rn(a.w * inv);
    qv[4] = __float2int_rn(b.x * inv);  qv[5] = __float2int_rn(b.y * inv);
    qv[6] = __float2int_rn(b.z * inv);  qv[7] = __float2int_rn(b.w * inv);

    int sq = 0;
    #pragma unroll
    for (int i = 0; i < 8; ++i) sq += qv[i] * qv[i];
    #pragma unroll
    for (int m = 32; m; m >>= 1) sq += __shfl_xor(sq, m, 64);
    if (lane == 0)
        g[row] = 3.7982825268f * __frsqrt_rn((float)sq);   // sqrt(10*log2e)/|q|

    const uint32_t lo = (uint32_t)((qv[0] & 255) | ((qv[1] & 255) << 8)
                       | ((qv[2] & 255) << 16) | ((qv[3] & 255) << 24));
    const uint32_t hi = (uint32_t)((qv[4] & 255) | ((qv[5] & 255) << 8)
                       | ((qv[6] & 255) << 16) | ((qv[7] & 255) << 24));
    // kc = lane>>3; q = (lane>>1)&3; ko8 = (lane&1)*8
    const size_t idx = (size_t)(row >> 7) * PANEL_BYTES + (size_t)(lane >> 3) * 8192
                     + (size_t)((lane >> 1) & 3) * 2048 + (row & 127) * 16 + (lane & 1) * 8;
    *(uint2*)(Fn2 + idx) = make_uint2(lo, hi);
}

// R12 K-loop shell (triple-buffered LDS, prefetch distance 2, raw
// `s_waitcnt vmcnt(4); s_barrier`) with i8 K=64 MFMA + per-row renormalized
// exp + R13 tree-packed epilogue. No atomics / no fences; disjoint writers.
__global__ __launch_bounds__(256, 3)
void cc_gemm(const uint8_t* __restrict__ Fn2, const int* __restrict__ cl,
             const float* __restrict__ g,
             float* __restrict__ Pt, float* __restrict__ Pp) {
    __shared__ __align__(16) uint8_t smem[6 * KCHUNK_BYTES];   // As[3] | Bs[3], 48 KB
    __shared__ int crow[TILE], ccol[TILE];
    __shared__ float gr[TILE], gc[TILE];
    uint8_t* As = smem;
    uint8_t* Bs = smem + 3 * KCHUNK_BYTES;
    // epilogue scratch aliases buffer 0 (dead after the last K-iteration barrier)
    float2 (*rsum)[TILE] = (float2 (*)[TILE])(smem);            // 2 KB
    float2 (*csum)[TILE] = (float2 (*)[TILE])(smem + 4096);     // 2 KB

    const int tid  = threadIdx.x;
    const int wave = tid >> 6;
    const int lane = tid & 63;

    int rem = blockIdx.x, bm = 0;
    while (rem >= NTB - bm) { rem -= NTB - bm; ++bm; }
    const int bn = bm + rem;
    const bool diag = (bm == bn);

    if (tid < TILE) { crow[tid] = cl[bm * TILE + tid];  gr[tid] = g[bm * TILE + tid]; }
    else { const int c = tid - TILE;  ccol[c] = cl[bn * TILE + c];  gc[c] = g[bn * TILE + c]; }

    const int wr = wave >> 1, wc = wave & 1;    // 2x2 wave grid, 64x64 each
    const int q   = lane >> 4;
    const int n15 = lane & 15;

    v4i acc[4][4];
    #pragma unroll
    for (int t = 0; t < 4; ++t)
        #pragma unroll
        for (int u = 0; u < 4; ++u) acc[t][u] = (v4i)(0);

    const uint8_t* Ag = Fn2 + (size_t)bm * PANEL_BYTES;
    const uint8_t* Bg = Fn2 + (size_t)bn * PANEL_BYTES;

    auto stage = [&](int kc, int buf) {
        const uint8_t* ga = Ag + kc * KCHUNK_BYTES;
        const uint8_t* gb = Bg + kc * KCHUNK_BYTES;
        #pragma unroll
        for (int i = 0; i < 2; ++i) {
            const int off = (wave * 2 + i) * 1024;
            gload_lds16(ga + off + lane * 16, As + buf * KCHUNK_BYTES + off);
            gload_lds16(gb + off + lane * 16, Bs + buf * KCHUNK_BYTES + off);
        }
    };

    stage(0, 0);   // distance-2 pipeline prologue
    stage(1, 1);

    #pragma unroll
    for (int kc = 0; kc < NKC; ++kc) {
        const int b = kc % 3;
        if (kc < NKC - 1)
            asm volatile("s_waitcnt vmcnt(4) lgkmcnt(0)\n\ts_barrier" ::: "memory");
        else
            asm volatile("s_waitcnt vmcnt(0) lgkmcnt(0)\n\ts_barrier" ::: "memory");
        if (kc + 2 < NKC) stage(kc + 2, (kc + 2) % 3);
        const int base = b * KCHUNK_BYTES + q * 2048 + n15 * 16;
        v4i af[4], bfr[4];
        #pragma unroll
        for (int t = 0; t < 4; ++t)
            af[t] = *(const v4i*)&As[base + (wr * 64 + t * 16) * 16];
        #pragma unroll
        for (int u = 0; u < 4; ++u)
            bfr[u] = *(const v4i*)&Bs[base + (wc * 64 + u * 16) * 16];
        #pragma unroll
        for (int t = 0; t < 4; ++t)
            #pragma unroll
            for (int u = 0; u < 4; ++u)
                acc[t][u] = __builtin_amdgcn_mfma_i32_16x16x64_i8(af[t], bfr[u], acc[t][u], 0, 0, 0);
    }

    __syncthreads();   // all LDS buffer reads done; safe to alias rsum/csum

    // epilogue: e = exp2(dot_q * g_i * g_j); C layout col=lane&15, row=q*4+reg
    int cc[4];  float gcu[4];
    #pragma unroll
    for (int u = 0; u < 4; ++u) {
        const int c = wc * 64 + u * 16 + n15;
        cc[u] = ccol[c];  gcu[u] = gc[c];
    }

    float ra[16], rp[16];            // per-lane row partials, idx = t*4+r
    float ce[4] = {0.f, 0.f, 0.f, 0.f};
    float cp2[4] = {0.f, 0.f, 0.f, 0.f};

    #pragma unroll
    for (int t = 0; t < 4; ++t) {
        #pragma unroll
        for (int r = 0; r < 4; ++r) {
            const int lr  = wr * 64 + t * 16 + q * 4 + r;
            const int myc = crow[lr];
            const float g_r = gr[lr];
            float te = 0.0f, tp = 0.0f;
            #pragma unroll
            for (int u = 0; u < 4; ++u) {
                const float e  = exp2f((float)acc[t][u][r] * (g_r * gcu[u]));
                const float ep = (cc[u] == myc) ? e : 0.0f;
                te += e;  tp += ep;
                ce[u] += e;  cp2[u] += ep;
            }
            ra[t * 4 + r] = te;  rp[t * 4 + r] = tp;
        }
    }

    // tree-packed reduction (R13-verified): 16 row sums over 16 lanes,
    // 15 shuffles/array. After stage m the kept index gains `half` iff lane&m.
    {
        int len = 16;
        #pragma unroll
        for (int m = 1; m <= 8; m <<= 1) {
            const int half = len >> 1;
            const bool hiL = (lane & m) != 0;
            #pragma unroll
            for (int j = 0; j < half; ++j) {
                float sa = hiL ? ra[j] : ra[j + half];
                float sp = hiL ? rp[j] : rp[j + half];
                sa = __shfl_xor(sa, m, 64);
                sp = __shfl_xor(sp, m, 64);
                ra[j] = (hiL ? ra[j + half] : ra[j]) + sa;
                rp[j] = (hiL ? rp[j + half] : rp[j]) + sp;
            }
            len = half;
        }
        const int idx = ((n15 & 1) << 3) | ((n15 & 2) << 1) | ((n15 & 4) >> 1) | ((n15 & 8) >> 3);
        const int row = wr * 64 + (idx >> 2) * 16 + q * 4 + (idx & 3);
        rsum[wc][row] = make_float2(ra[0], rp[0]);
    }

    // column sums: 4 values over the 4 q-groups (masks 16, 32), 3 shuffles/array
    if (!diag) {
        int len = 4;
        #pragma unroll
        for (int m = 16; m <= 32; m <<= 1) {
            const int half = len >> 1;
            const bool hiL = (lane & m) != 0;
            #pragma unroll
            for (int j = 0; j < half; ++j) {
                float se = hiL ? ce[j] : ce[j + half];
                float sp = hiL ? cp2[j] : cp2[j + half];
                se = __shfl_xor(se, m, 64);
                sp = __shfl_xor(sp, m, 64);
                ce[j] = (hiL ? ce[j + half] : ce[j]) + se;
                cp2[j] = (hiL ? cp2[j + half] : cp2[j]) + sp;
            }
            len = half;
        }
        const int u = (((lane >> 4) & 1) << 1) | ((lane >> 5) & 1);
        const int col = wc * 64 + u * 16 + n15;
        csum[wr][col] = make_float2(ce[0], cp2[0]);
    }

    __syncthreads();
    if (tid < TILE) {
        const float2 r0 = rsum[0][tid], r1 = rsum[1][tid];
        const size_t o = (size_t)bn * N + bm * TILE + tid;
        Pt[o] = r0.x + r1.x;  Pp[o] = r0.y + r1.y;
    } else if (!diag) {
        const int c = tid - TILE;
        const float2 c0 = csum[0][c], c1 = csum[1][c];
        const size_t o = (size_t)bm * N + bn * TILE + c;
        Pt[o] = c0.x + c1.x;  Pp[o] = c0.y + c1.y;
    }
}

// 32 blocks x 256: row i sums its 64 slices, loss, block-reduce, atomicAdd out
__global__ void cc_finalize(const float* __restrict__ Pt, const float* __restrict__ Pp,
                            float* __restrict__ out) {
    __shared__ float red[4];
    const int i = blockIdx.x * 256 + threadIdx.x;
    float tv = 0.0f, pv = 0.0f;
    #pragma unroll 8
    for (int s = 0; s < NTB; ++s) {
        tv += Pt[(size_t)s * N + i];
        pv += Pp[(size_t)s * N + i];
    }
    float l = __logf(tv + 1e-8f) - __logf(pv);
    #pragma unroll
    for (int m = 32; m; m >>= 1) l += __shfl_xor(l, m, 64);
    const int wv = threadIdx.x >> 6, lane = threadIdx.x & 63;
    if (lane == 0) red[wv] = l;
    __syncthreads();
    if (threadIdx.x == 0) atomicAdd(out, red[0] + red[1] + red[2] + red[3]);
}

extern "C" void kernel_launch(void* const* d_in, const int* in_sizes, int n_in,
                              void* d_out, int out_size, void* d_ws, size_t ws_size,
                              hipStream_t stream) {
    const float* F  = (const float*)d_in[0];
    const int*   cl = (const int*)d_in[1];
    float* out = (float*)d_out;

    uint8_t* Fn2 = (uint8_t*)d_ws;                               // 4 MB i8 swizzled
    float* Pt  = (float*)((char*)d_ws + (size_t)N * D);          // 2 MB
    float* Pp  = Pt + (size_t)NTB * N;                           // 2 MB
    float* g   = Pp + (size_t)NTB * N;                           // 32 KB per-row renorm

    cc_normalize<<<N / 4, 256, 0, stream>>>(F, Fn2, g, out);
    cc_gemm<<<NBLK, 256, 0, stream>>>(Fn2, cl, g, Pt, Pp);
    cc_finalize<<<N / 256, 256, 0, stream>>>(Pt, Pp, out);
}

// Round 17
// 109.567 us; speedup vs baseline: 1.2971x; 1.2971x over previous
//
#include <hip/hip_runtime.h>
#include <hip/hip_bf16.h>
#include <stdint.h>

#define N 8192
#define D 512
#define TILE 128
#define BK 64
#define NKC (D / BK)                  // 8 K-chunks
#define NTB (N / TILE)                // 64 tile-rows (= #slices)
#define NBLK (NTB * (NTB + 1) / 2)    // 2080 upper-tri blocks
#define PANEL_BYTES (TILE * D)        // 65536 B per 128-row fp8 panel
#define KCHUNK_BYTES (TILE * BK)      // 8192 B per staged fp8 tile

typedef long long i64;
typedef __attribute__((ext_vector_type(4))) float f32x4;

// async global->LDS, 16B per lane; LDS dest = wave-uniform base + lane*16
__device__ __forceinline__ void gload_lds16(const void* gp, const void* lp) {
    auto g = (const __attribute__((address_space(1))) void*)(uintptr_t)gp;
    auto l = (__attribute__((address_space(3))) void*)(uintptr_t)lp;
    __builtin_amdgcn_global_load_lds(g, l, 16, 0, 0);
}

// Fn2 swizzled fp8 layout (R7, verified):
//   byte(p, kc, ks, q, lr) = p*65536 + kc*8192 + ks*4096 + q*1024 + lr*8
// values = fp8_e4m3(16 * normalized_row)
__global__ void cc_normalize(const float* __restrict__ F, uint8_t* __restrict__ Fn2,
                             float* __restrict__ out) {
    if (blockIdx.x == 0 && threadIdx.x == 0) out[0] = 0.0f;
    const int row  = blockIdx.x * 4 + (threadIdx.x >> 6);
    const int lane = threadIdx.x & 63;
    const float* p = F + (size_t)row * D + lane * 8;
    float4 a = *(const float4*)p;
    float4 b = *(const float4*)(p + 4);
    float ss = a.x*a.x + a.y*a.y + a.z*a.z + a.w*a.w
             + b.x*b.x + b.y*b.y + b.z*b.z + b.w*b.w;
    #pragma unroll
    for (int m = 32; m; m >>= 1) ss += __shfl_xor(ss, m, 64);
    const float inv = 16.0f / fmaxf(sqrtf(ss), 1e-12f);
    int lo = 0, hi = 0;
    lo = __builtin_amdgcn_cvt_pk_fp8_f32(a.x*inv, a.y*inv, lo, false);
    lo = __builtin_amdgcn_cvt_pk_fp8_f32(a.z*inv, a.w*inv, lo, true);
    hi = __builtin_amdgcn_cvt_pk_fp8_f32(b.x*inv, b.y*inv, hi, false);
    hi = __builtin_amdgcn_cvt_pk_fp8_f32(b.z*inv, b.w*inv, hi, true);
    const size_t idx = (size_t)(row >> 7) * PANEL_BYTES + (size_t)lane * 1024 + (row & 127) * 8;
    *(int2*)(Fn2 + idx) = make_int2(lo, hi);
}

// R12 K-loop (triple-buffered LDS, prefetch distance 2, raw
// `s_waitcnt vmcnt(4); s_barrier` so the newest stage stays in flight)
// + R13's correctness-verified tree-packed epilogue reduction.
// No atomics / no fences; block (bm,bn) writes row sums -> slice bn,
// col sums -> slice bm (disjoint-writer scheme).
__global__ __launch_bounds__(256, 3)
void cc_gemm(const uint8_t* __restrict__ Fn2, const int* __restrict__ cl,
             float* __restrict__ Pt, float* __restrict__ Pp) {
    __shared__ __align__(16) uint8_t smem[6 * KCHUNK_BYTES];   // As[3] | Bs[3], 48 KB
    __shared__ int crow[TILE], ccol[TILE];
    uint8_t* As = smem;
    uint8_t* Bs = smem + 3 * KCHUNK_BYTES;
    // epilogue scratch aliases buffer 0 (dead after the last K-iteration barrier)
    float2 (*rsum)[TILE] = (float2 (*)[TILE])(smem);            // 2 KB
    float2 (*csum)[TILE] = (float2 (*)[TILE])(smem + 4096);     // 2 KB

    const int tid  = threadIdx.x;
    const int wave = tid >> 6;
    const int lane = tid & 63;

    int rem = blockIdx.x, bm = 0;
    while (rem >= NTB - bm) { rem -= NTB - bm; ++bm; }
    const int bn = bm + rem;
    const bool diag = (bm == bn);

    if (tid < TILE)            crow[tid]        = cl[bm * TILE + tid];
    else                       ccol[tid - TILE] = cl[bn * TILE + (tid - TILE)];

    const int wr = wave >> 1, wc = wave & 1;    // 2x2 wave grid, 64x64 each
    const int q   = lane >> 4;
    const int n15 = lane & 15;

    f32x4 acc[4][4];
    #pragma unroll
    for (int t = 0; t < 4; ++t)
        #pragma unroll
        for (int u = 0; u < 4; ++u) acc[t][u] = (f32x4)(0.0f);

    const uint8_t* Ag = Fn2 + (size_t)bm * PANEL_BYTES;
    const uint8_t* Bg = Fn2 + (size_t)bn * PANEL_BYTES;

    auto stage = [&](int kc, int buf) {
        const uint8_t* ga = Ag + kc * KCHUNK_BYTES;
        const uint8_t* gb = Bg + kc * KCHUNK_BYTES;
        #pragma unroll
        for (int i = 0; i < 2; ++i) {
            const int off = (wave * 2 + i) * 1024;
            gload_lds16(ga + off + lane * 16, As + buf * KCHUNK_BYTES + off);
            gload_lds16(gb + off + lane * 16, Bs + buf * KCHUNK_BYTES + off);
        }
    };

    stage(0, 0);   // distance-2 pipeline prologue
    stage(1, 1);

    #pragma unroll
    for (int kc = 0; kc < NKC; ++kc) {
        const int b = kc % 3;
        // crow/ccol ds_writes are covered by lgkmcnt(0) before the first barrier
        if (kc < NKC - 1)
            asm volatile("s_waitcnt vmcnt(4) lgkmcnt(0)\n\ts_barrier" ::: "memory");
        else
            asm volatile("s_waitcnt vmcnt(0) lgkmcnt(0)\n\ts_barrier" ::: "memory");
        if (kc + 2 < NKC) stage(kc + 2, (kc + 2) % 3);
        #pragma unroll
        for (int ks = 0; ks < 2; ++ks) {
            const int base = b * KCHUNK_BYTES + ks * 4096 + q * 1024 + n15 * 8;
            i64 af[4], bfr[4];
            #pragma unroll
            for (int t = 0; t < 4; ++t)
                af[t] = *(const i64*)&As[base + (wr * 64 + t * 16) * 8];
            #pragma unroll
            for (int u = 0; u < 4; ++u)
                bfr[u] = *(const i64*)&Bs[base + (wc * 64 + u * 16) * 8];
            #pragma unroll
            for (int t = 0; t < 4; ++t)
                #pragma unroll
                for (int u = 0; u < 4; ++u)
                    acc[t][u] = __builtin_amdgcn_mfma_f32_16x16x32_fp8_fp8(af[t], bfr[u], acc[t][u], 0, 0, 0);
        }
    }

    __syncthreads();   // all LDS buffer reads done; safe to alias rsum/csum

    // epilogue: sim = dot/256; e = exp2(dot * 10*log2(e)/256)
    // C layout col=lane&15, row=q*4+reg
    const float SC = 0.05635527503472514f;
    int cc[4];
    #pragma unroll
    for (int u = 0; u < 4; ++u) cc[u] = ccol[wc * 64 + u * 16 + n15];

    float ra[16], rp[16];            // per-lane row partials, idx = t*4+r
    float ce[4] = {0.f, 0.f, 0.f, 0.f};
    float cp2[4] = {0.f, 0.f, 0.f, 0.f};

    #pragma unroll
    for (int t = 0; t < 4; ++t) {
        #pragma unroll
        for (int r = 0; r < 4; ++r) {
            const int myc = crow[wr * 64 + t * 16 + q * 4 + r];
            float te = 0.0f, tp = 0.0f;
            #pragma unroll
            for (int u = 0; u < 4; ++u) {
                const float e  = exp2f(acc[t][u][r] * SC);
                const float ep = (cc[u] == myc) ? e : 0.0f;
                te += e;  tp += ep;
                ce[u] += e;  cp2[u] += ep;
            }
            ra[t * 4 + r] = te;  rp[t * 4 + r] = tp;
        }
    }

    // tree-packed reduction (R13-verified): 16 row sums over 16 lanes,
    // 15 shuffles/array. After stage m the kept index gains `half` iff lane&m.
    {
        int len = 16;
        #pragma unroll
        for (int m = 1; m <= 8; m <<= 1) {
            const int half = len >> 1;
            const bool hiL = (lane & m) != 0;
            #pragma unroll
            for (int j = 0; j < half; ++j) {
                float sa = hiL ? ra[j] : ra[j + half];
                float sp = hiL ? rp[j] : rp[j + half];
                sa = __shfl_xor(sa, m, 64);
                sp = __shfl_xor(sp, m, 64);
                ra[j] = (hiL ? ra[j + half] : ra[j]) + sa;
                rp[j] = (hiL ? rp[j + half] : rp[j]) + sp;
            }
            len = half;
        }
        const int idx = ((n15 & 1) << 3) | ((n15 & 2) << 1) | ((n15 & 4) >> 1) | ((n15 & 8) >> 3);
        const int row = wr * 64 + (idx >> 2) * 16 + q * 4 + (idx & 3);
        rsum[wc][row] = make_float2(ra[0], rp[0]);
    }

    // column sums: 4 values over the 4 q-groups (masks 16, 32), 3 shuffles/array
    if (!diag) {
        int len = 4;
        #pragma unroll
        for (int m = 16; m <= 32; m <<= 1) {
            const int half = len >> 1;
            const bool hiL = (lane & m) != 0;
            #pragma unroll
            for (int j = 0; j < half; ++j) {
                float se = hiL ? ce[j] : ce[j + half];
                float sp = hiL ? cp2[j] : cp2[j + half];
                se = __shfl_xor(se, m, 64);
                sp = __shfl_xor(sp, m, 64);
                ce[j] = (hiL ? ce[j + half] : ce[j]) + se;
                cp2[j] = (hiL ? cp2[j + half] : cp2[j]) + sp;
            }
            len = half;
        }
        const int u = (((lane >> 4) & 1) << 1) | ((lane >> 5) & 1);
        const int col = wc * 64 + u * 16 + n15;
        csum[wr][col] = make_float2(ce[0], cp2[0]);
    }

    __syncthreads();
    if (tid < TILE) {
        const float2 r0 = rsum[0][tid], r1 = rsum[1][tid];
        const size_t o = (size_t)bn * N + bm * TILE + tid;
        Pt[o] = r0.x + r1.x;  Pp[o] = r0.y + r1.y;
    } else if (!diag) {
        const int c = tid - TILE;
        const float2 c0 = csum[0][c], c1 = csum[1][c];
        const size_t o = (size_t)bm * N + bn * TILE + c;
        Pt[o] = c0.x + c1.x;  Pp[o] = c0.y + c1.y;
    }
}

// 32 blocks x 256: row i sums its 64 slices, loss, block-reduce, atomicAdd out
__global__ void cc_finalize(const float* __restrict__ Pt, const float* __restrict__ Pp,
                            float* __restrict__ out) {
    __shared__ float red[4];
    const int i = blockIdx.x * 256 + threadIdx.x;
    float tv = 0.0f, pv = 0.0f;
    #pragma unroll 8
    for (int s = 0; s < NTB; ++s) {
        tv += Pt[(size_t)s * N + i];
        pv += Pp[(size_t)s * N + i];
    }
    float l = __logf(tv + 1e-8f) - __logf(pv);
    #pragma unroll
    for (int m = 32; m; m >>= 1) l += __shfl_xor(l, m, 64);
    const int wv = threadIdx.x >> 6, lane = threadIdx.x & 63;
    if (lane == 0) red[wv] = l;
    __syncthreads();
    if (threadIdx.x == 0) atomicAdd(out, red[0] + red[1] + red[2] + red[3]);
}

extern "C" void kernel_launch(void* const* d_in, const int* in_sizes, int n_in,
                              void* d_out, int out_size, void* d_ws, size_t ws_size,
                              hipStream_t stream) {
    const float* F  = (const float*)d_in[0];
    const int*   cl = (const int*)d_in[1];
    float* out = (float*)d_out;

    uint8_t* Fn2 = (uint8_t*)d_ws;                               // 4 MB fp8 swizzled
    float* Pt  = (float*)((char*)d_ws + (size_t)N * D);          // 2 MB
    float* Pp  = Pt + (size_t)NTB * N;                           // 2 MB

    cc_normalize<<<N / 4, 256, 0, stream>>>(F, Fn2, out);
    cc_gemm<<<NBLK, 256, 0, stream>>>(Fn2, cl, Pt, Pp);
    cc_finalize<<<N / 256, 256, 0, stream>>>(Pt, Pp, out);
}